// Round 16
// baseline (99.639 us; speedup 1.0000x reference)
//
#include <hip/hip_runtime.h>
#include <hip/hip_bf16.h>

// B=8, S=4096, H=8, HKV=2, D=64, HID=512. M_TOT=32768, K=512.
// Pipeline:
//   K0 convert_x2  : x f32 -> xb_t bf16 tiled (mblk256, kt, kg, row) via LDS
//   K1 transpose_w : weights -> wt bf16 (panel layout; kt-chunks contiguous)
//   K2 gemm2b<6,0,true>  : xb_t @ wt[0..5] -> qkv bf16 [128x128, 2 blk/CU]
//   K3 attn_heads  : RoPE + analytic GQA -> out2 (aliases xb_t)
//   K4 gemm2b<4,6,false> : out2 @ wt[6..9] -> d_out f32 [same structure,
//                          A staged per-lane from row-major out2]
// gemm2b: BM128 x BN128, BK=64 (8 K-tiles), 2-buffer LDS (64KB) -> 2
// blocks/CU; phases of independent blocks interleave (m114 overlap; r14
// showed 1-block/CU serializes LDS vs MFMA bursts; r15 confirmed +7us).
// 4 waves 2m x 2n, wave 64x64, acc[4][4]. Per K-tile: phase A {ds_read
// kg0..3, stage(kt+1), lgkm0, 16 MFMA}, phase B {ds_read kg4..7, lgkm0,
// 16 MFMA}, vmcnt(0)+barrier once per tile.
// TILED=false: A-stage computes per-lane row-major source addresses
// (global_load_lds source is per-lane; LDS dest stays linear) — avoids
// re-tiling out2 (attn's 1KB-contiguous stores preserved).
// Scramble (ref transpose(0,2,1,3).reshape): attnout[b,t,h,d] ->
//   out2 row = h*512 + t/8, col = (t%8)*64 + d (per batch).

#define M_TOT 32768

typedef __bf16 bf16x8 __attribute__((ext_vector_type(8)));
typedef float f32x4 __attribute__((ext_vector_type(4)));
typedef unsigned short ushort8 __attribute__((ext_vector_type(8)));

__device__ __forceinline__ void gload_lds16(const __hip_bfloat16* g,
                                            __hip_bfloat16* l) {
  __builtin_amdgcn_global_load_lds(
      (const __attribute__((address_space(1))) unsigned int*)g,
      (__attribute__((address_space(3))) unsigned int*)l, 16, 0, 0);
}

__device__ __forceinline__ float bf2f(unsigned short u) {
  union { unsigned int i; float f; } c;
  c.i = (unsigned int)u << 16;
  return c.f;
}

__device__ __forceinline__ bf16x8 cvt8(float4 a, float4 b) {
  bf16x8 r;
  r[0] = (__bf16)a.x; r[1] = (__bf16)a.y; r[2] = (__bf16)a.z; r[3] = (__bf16)a.w;
  r[4] = (__bf16)b.x; r[5] = (__bf16)b.y; r[6] = (__bf16)b.z; r[7] = (__bf16)b.w;
  return r;
}

// x (row-major f32) -> xb_t tiled bf16: tile (mblk 0..127, kt 0..7) holds
// slots (kg 0..7, row 0..255): elem((mblk*8+kt)*16384 + (kg*256+row)*8 + e)
// = x[mblk*256+row][kt*64+kg*8+e].
__global__ __launch_bounds__(256) void convert_x2(
    const float* __restrict__ x, __hip_bfloat16* __restrict__ xbt) {
  __shared__ __hip_bfloat16 Lt[16384];  // 32KB
  const int bid = blockIdx.x;           // = mblk*8 + kt
  const int mblk = bid >> 3, kt = bid & 7;
  const int t = threadIdx.x;
  const int koct = t & 7;
#pragma unroll
  for (int p = 0; p < 8; ++p) {
    int r = p * 32 + (t >> 3);
    const float* src = x + (size_t)(mblk * 256 + r) * 512 + kt * 64 + koct * 8;
    float4 f0 = *(const float4*)src;
    float4 f1 = *(const float4*)(src + 4);
    *(bf16x8*)&Lt[(koct * 256 + r) * 8] = cvt8(f0, f1);
  }
  __syncthreads();
  __hip_bfloat16* outb = xbt + (size_t)bid * 16384;
#pragma unroll
  for (int j = 0; j < 8; ++j) {
    int s = j * 256 + t;
    *(bf16x8*)(outb + (size_t)s * 8) = *(const bf16x8*)&Lt[s * 8];
  }
}

// wt pre-tiled, 128-col panels: col n (0..1279), k (0..511):
// elem = (n>>7)*65536 + ((k>>3)*128 + (n&127))*8 + (k&7).
__global__ __launch_bounds__(256) void transpose_w(
    const float* __restrict__ wq, const float* __restrict__ wk,
    const float* __restrict__ wv, const float* __restrict__ wo,
    __hip_bfloat16* __restrict__ wt) {
  __shared__ float tile[32][33];
  int n0 = blockIdx.x * 32, k0 = blockIdx.y * 32;
  const float* W;
  int ld, nc;
  if (n0 < 512)      { W = wq; ld = 512; nc = n0; }
  else if (n0 < 640) { W = wk; ld = 128; nc = n0 - 512; }
  else if (n0 < 768) { W = wv; ld = 128; nc = n0 - 640; }
  else               { W = wo; ld = 512; nc = n0 - 768; }
  int x = threadIdx.x & 31, y = threadIdx.x >> 5;
#pragma unroll
  for (int i = 0; i < 4; ++i)
    tile[y + 8 * i][x] = W[(size_t)(k0 + y + 8 * i) * ld + nc + x];
  __syncthreads();
#pragma unroll
  for (int i = 0; i < 4; ++i) {
    int n = n0 + y + 8 * i, k = k0 + x;
    wt[((size_t)(n >> 7) << 16) + ((size_t)((k >> 3) * 128 + (n & 127))) * 8 +
       (k & 7)] = __float2bfloat16(tile[x][y + 8 * i]);
  }
}

// 128x128 2-blocks/CU GEMM. TILED: A = xb_t (256-row tiles, use half);
// !TILED: A row-major (per-lane source addressing, linear LDS dest).
// wt: per K-tile 8192-elem chunk at kt*8192. C row-major (N = NT*128).
template <int NT, int NB0, bool TILED, typename OutT>
__global__ __launch_bounds__(256, 2) void gemm2b(
    const __hip_bfloat16* __restrict__ At, const __hip_bfloat16* __restrict__ wt,
    OutT* __restrict__ C) {
  constexpr int N = NT * 128;
  __shared__ __hip_bfloat16 Al[2][8192];  // 2 x 16KB
  __shared__ __hip_bfloat16 Bd[2][8192];  // 2 x 16KB
  const int tid = threadIdx.x;
  const int lane = tid & 63;
  const int w = tid >> 6;             // 0..3
  const int wr = w >> 1, wc = w & 1;  // 2m x 2n
  constexpr int NWG = 256 * NT;
  const int ng = (blockIdx.x & 7) * (NWG / 8) + (blockIdx.x >> 3);
  const int mt = ng / NT;       // 0..255 (128-row tile)
  const int n0 = (ng % NT) * 128;
  const int m0 = mt * 128;
  const int half = mt & 1;
  const __hip_bfloat16* Abase = At + (size_t)(mt >> 1) * 8 * 16384;
  const __hip_bfloat16* Bbase = wt + ((size_t)(NB0 + ng % NT) << 16);

  const int kbq = lane >> 4, fr = lane & 15;
  f32x4 acc[4][4] = {};

  // stage K-tile kt into buf: 4 A + 4 B gloads per thread.
  auto stage = [&](int buf, int kt) {
    const __hip_bfloat16* Bs = Bbase + (size_t)kt * 8192;
#pragma unroll
    for (int j = 0; j < 4; ++j) {
      int s = j * 256 + tid;  // LDS slot kg*128+row, kg=s>>7, row=s&127
      const __hip_bfloat16* src;
      if constexpr (TILED) {
        int srcslot = ((s >> 7) << 8) + half * 128 + (s & 127);
        src = Abase + (size_t)kt * 16384 + (size_t)srcslot * 8;
      } else {
        src = At + (size_t)(m0 + (s & 127)) * 512 + kt * 64 + (s >> 7) * 8;
      }
      gload_lds16(src, &Al[buf][(j * 256 + w * 64) * 8]);
    }
#pragma unroll
    for (int j = 0; j < 4; ++j) {
      int s = j * 256 + tid;
      gload_lds16(Bs + (size_t)s * 8, &Bd[buf][(j * 256 + w * 64) * 8]);
    }
  };

  stage(0, 0);
  asm volatile("s_waitcnt vmcnt(0)" ::: "memory");
  __builtin_amdgcn_s_barrier();

#pragma unroll
  for (int kt = 0; kt < 8; ++kt) {
    const int cur = kt & 1;
    // ---- phase A: kg = kbq (0..3)
    {
      bf16x8 a[4], b[4];
#pragma unroll
      for (int mi = 0; mi < 4; ++mi)
        a[mi] = *(const bf16x8*)
            &Al[cur][(kbq * 128 + wr * 64 + mi * 16 + fr) * 8];
#pragma unroll
      for (int ni = 0; ni < 4; ++ni)
        b[ni] = *(const bf16x8*)
            &Bd[cur][(kbq * 128 + wc * 64 + ni * 16 + fr) * 8];
      if (kt < 7) stage(cur ^ 1, kt + 1);
      asm volatile("s_waitcnt lgkmcnt(0)" ::: "memory");
      __builtin_amdgcn_sched_barrier(0);
      __builtin_amdgcn_s_setprio(1);
#pragma unroll
      for (int mi = 0; mi < 4; ++mi)
#pragma unroll
        for (int ni = 0; ni < 4; ++ni)
          acc[mi][ni] = __builtin_amdgcn_mfma_f32_16x16x32_bf16(
              a[mi], b[ni], acc[mi][ni], 0, 0, 0);
      __builtin_amdgcn_s_setprio(0);
    }
    // ---- phase B: kg = 4 + kbq
    {
      bf16x8 a[4], b[4];
      const int kg = 4 + kbq;
#pragma unroll
      for (int mi = 0; mi < 4; ++mi)
        a[mi] = *(const bf16x8*)
            &Al[cur][(kg * 128 + wr * 64 + mi * 16 + fr) * 8];
#pragma unroll
      for (int ni = 0; ni < 4; ++ni)
        b[ni] = *(const bf16x8*)
            &Bd[cur][(kg * 128 + wc * 64 + ni * 16 + fr) * 8];
      asm volatile("s_waitcnt lgkmcnt(0)" ::: "memory");
      __builtin_amdgcn_sched_barrier(0);
      __builtin_amdgcn_s_setprio(1);
#pragma unroll
      for (int mi = 0; mi < 4; ++mi)
#pragma unroll
        for (int ni = 0; ni < 4; ++ni)
          acc[mi][ni] = __builtin_amdgcn_mfma_f32_16x16x32_bf16(
              a[mi], b[ni], acc[mi][ni], 0, 0, 0);
      __builtin_amdgcn_s_setprio(0);
    }
    if (kt < 7) {
      asm volatile("s_waitcnt vmcnt(0)" ::: "memory");  // stage(kt+1) landed
      __builtin_amdgcn_s_barrier();  // all waves done reading buf cur
    }
  }

  // C/D layout: col=lane&15, row=(lane>>4)*4+reg  [m89]
#pragma unroll
  for (int mi = 0; mi < 4; ++mi) {
#pragma unroll
    for (int ni = 0; ni < 4; ++ni) {
      int col = n0 + wc * 64 + ni * 16 + (lane & 15);
#pragma unroll
      for (int r = 0; r < 4; ++r) {
        int row = m0 + wr * 64 + mi * 16 + (lane >> 4) * 4 + r;
        if constexpr (sizeof(OutT) == 2)
          C[(size_t)row * N + col] = __float2bfloat16(acc[mi][ni][r]);
        else
          C[(size_t)row * N + col] = acc[mi][ni][r];
      }
    }
  }
}

// attn: 8 lanes per position; ushort8 loads; lane-local RoPE pairs;
// 3-hop shuffle dots; 1KB-contiguous stores.
__global__ __launch_bounds__(256) void attn_heads(
    const __hip_bfloat16* __restrict__ qkv, const float* __restrict__ fcos,
    const float* __restrict__ fsin, __hip_bfloat16* __restrict__ out2) {
  const int lane = threadIdx.x & 63;
  const int wvid = blockIdx.x * 4 + (threadIdx.x >> 6);
  const int pos = lane >> 3, dlane = lane & 7;
  const int gt = wvid * 8 + pos;
  const int b = gt >> 12, t = gt & 4095;
  const size_t row = (size_t)gt * 768;

  f32x4 c4 = *(const f32x4*)&fcos[(size_t)t * 32 + dlane * 4];
  f32x4 s4 = *(const f32x4*)&fsin[(size_t)t * 32 + dlane * 4];

  float q[8][8], k[2][8], v[2][8];
#pragma unroll
  for (int h = 0; h < 8; ++h) {
    ushort8 u = *(const ushort8*)&qkv[row + h * 64 + dlane * 8];
#pragma unroll
    for (int j = 0; j < 4; ++j) {
      float xr = bf2f(u[2 * j]), xi = bf2f(u[2 * j + 1]);
      q[h][2 * j] = xr * c4[j] - xi * s4[j];
      q[h][2 * j + 1] = xr * s4[j] + xi * c4[j];
    }
  }
#pragma unroll
  for (int c = 0; c < 2; ++c) {
    ushort8 uk = *(const ushort8*)&qkv[row + 512 + c * 64 + dlane * 8];
    ushort8 uv = *(const ushort8*)&qkv[row + 640 + c * 64 + dlane * 8];
#pragma unroll
    for (int j = 0; j < 4; ++j) {
      float xr = bf2f(uk[2 * j]), xi = bf2f(uk[2 * j + 1]);
      k[c][2 * j] = xr * c4[j] - xi * s4[j];
      k[c][2 * j + 1] = xr * s4[j] + xi * c4[j];
    }
#pragma unroll
    for (int j = 0; j < 8; ++j) v[c][j] = bf2f(uv[j]);
  }

  float dot[8][2];
#pragma unroll
  for (int h = 0; h < 8; ++h)
#pragma unroll
    for (int c = 0; c < 2; ++c) {
      float p = 0.f;
#pragma unroll
      for (int j = 0; j < 8; ++j) p += q[h][j] * k[c][j];
      p += __shfl_xor(p, 1);
      p += __shfl_xor(p, 2);
      p += __shfl_xor(p, 4);
      dot[h][c] = p * 0.125f;
    }

#pragma unroll
  for (int h = 0; h < 8; ++h) {
    int c0 = (h + 1 < 4) ? (h + 1) : 4;
    int c1 = (h + 1) - c0;
    float w0, w1;
    if (c1 > 0) {
      float s0 = dot[h][0], s1 = dot[h][1];
      float m = fmaxf(s0, s1);
      float e0 = (float)c0 * expf(s0 - m), e1 = (float)c1 * expf(s1 - m);
      float inv = 1.f / (e0 + e1);
      w0 = e0 * inv;
      w1 = e1 * inv;
    } else {
      w0 = 1.f;
      w1 = 0.f;
    }
    ushort8 o;
#pragma unroll
    for (int j = 0; j < 8; ++j) {
      __hip_bfloat16 ob = __float2bfloat16(w0 * v[0][j] + w1 * v[1][j]);
      o[j] = *(unsigned short*)&ob;
    }
    *(ushort8*)&out2[((size_t)(b * 4096 + h * 512 + (t >> 3))) * 512 +
                     pos * 64 + dlane * 8] = o;
  }
}

extern "C" void kernel_launch(void* const* d_in, const int* in_sizes, int n_in,
                              void* d_out, int out_size, void* d_ws,
                              size_t ws_size, hipStream_t stream) {
  const float* x    = (const float*)d_in[0];
  const float* fcos = (const float*)d_in[1];
  const float* fsin = (const float*)d_in[2];
  const float* wq   = (const float*)d_in[3];
  const float* wk   = (const float*)d_in[4];
  const float* wv   = (const float*)d_in[5];
  const float* wo   = (const float*)d_in[6];
  float* out = (float*)d_out;

  __hip_bfloat16* xbt  = (__hip_bfloat16*)d_ws;  // 32MB (tiled)
  __hip_bfloat16* out2 = xbt;                     // alias (dead after gemm6)
  __hip_bfloat16* qkv  = (__hip_bfloat16*)((char*)d_ws + (size_t)M_TOT * 512 * 2);  // 48MB
  __hip_bfloat16* wt   = (__hip_bfloat16*)((char*)d_ws + (size_t)M_TOT * 512 * 2 +
                                           (size_t)M_TOT * 768 * 2);  // 1.31MB

  convert_x2<<<dim3(1024), 256, 0, stream>>>(x, xbt);
  transpose_w<<<dim3(1280 / 32, 512 / 32), 256, 0, stream>>>(wq, wk, wv, wo, wt);
  gemm2b<6, 0, true, __hip_bfloat16><<<dim3(1536), 256, 0, stream>>>(xbt, wt, qkv);
  attn_heads<<<dim3(M_TOT / 8 / 4), 256, 0, stream>>>(qkv, fcos, fsin, out2);
  gemm2b<4, 6, false, float><<<dim3(1024), 256, 0, stream>>>(out2, wt, out);
}

// Round 17
// 92.507 us; speedup vs baseline: 1.0771x; 1.0771x over previous
//
#include <hip/hip_runtime.h>
#include <hip/hip_bf16.h>

// B=8, S=4096, H=8, HKV=2, D=64, HID=512. M_TOT=32768, K=512.
// Pipeline:
//   K0 convert_x2  : x f32 -> xb_t bf16 tiled (mblk256, kt, kg, row) via LDS
//   K1 transpose_w : weights -> wt bf16 (panel layout; kt-chunks contiguous)
//   K2 gemm2b<6,0> : xb_t @ wt[0..5] -> qkv bf16 [128x128, 2 blk/CU]
//   K3 attn_heads  : RoPE + analytic GQA -> out2 (row-major, aliases xb_t)
//   K4 gemm_persist<4,6,4,false> : out2 @ wt[6..9] -> d_out f32 (r13 struct,
//                    reverted: r16's row-major per-lane staging = 64-line
//                    gather per gload -> 4x L2 requests, +7us)
// gemm2b: BM128 x BN128, BK=64 (8 K-tiles), 2-buffer LDS (64KB) -> 2
// blocks/CU (m114 cross-block overlap, r15 win). 4 waves 2m x 2n, acc[4][4].
// r17: manual lgkmcnt(0)+sched_barrier pins before MFMA clusters REMOVED —
// ds_reads are plain C++ loads, compiler emits fine-grained lgkmcnt and can
// pipeline phase-B reads under phase-A MFMAs. The vmcnt(0):::"memory" at
// tile end still fences buffer swaps (no hoist across barrier).
// Scramble (ref transpose(0,2,1,3).reshape): attnout[b,t,h,d] ->
//   out2 row = h*512 + t/8, col = (t%8)*64 + d (per batch).

#define M_TOT 32768

typedef __bf16 bf16x8 __attribute__((ext_vector_type(8)));
typedef float f32x4 __attribute__((ext_vector_type(4)));
typedef unsigned short ushort8 __attribute__((ext_vector_type(8)));

__device__ __forceinline__ void gload_lds16(const __hip_bfloat16* g,
                                            __hip_bfloat16* l) {
  __builtin_amdgcn_global_load_lds(
      (const __attribute__((address_space(1))) unsigned int*)g,
      (__attribute__((address_space(3))) unsigned int*)l, 16, 0, 0);
}

__device__ __forceinline__ float bf2f(unsigned short u) {
  union { unsigned int i; float f; } c;
  c.i = (unsigned int)u << 16;
  return c.f;
}

__device__ __forceinline__ bf16x8 cvt8(float4 a, float4 b) {
  bf16x8 r;
  r[0] = (__bf16)a.x; r[1] = (__bf16)a.y; r[2] = (__bf16)a.z; r[3] = (__bf16)a.w;
  r[4] = (__bf16)b.x; r[5] = (__bf16)b.y; r[6] = (__bf16)b.z; r[7] = (__bf16)b.w;
  return r;
}

// x (row-major f32) -> xb_t tiled bf16: tile (mblk 0..127, kt 0..7) holds
// slots (kg 0..7, row 0..255): elem((mblk*8+kt)*16384 + (kg*256+row)*8 + e)
// = x[mblk*256+row][kt*64+kg*8+e].
__global__ __launch_bounds__(256) void convert_x2(
    const float* __restrict__ x, __hip_bfloat16* __restrict__ xbt) {
  __shared__ __hip_bfloat16 Lt[16384];  // 32KB
  const int bid = blockIdx.x;           // = mblk*8 + kt
  const int mblk = bid >> 3, kt = bid & 7;
  const int t = threadIdx.x;
  const int koct = t & 7;
#pragma unroll
  for (int p = 0; p < 8; ++p) {
    int r = p * 32 + (t >> 3);
    const float* src = x + (size_t)(mblk * 256 + r) * 512 + kt * 64 + koct * 8;
    float4 f0 = *(const float4*)src;
    float4 f1 = *(const float4*)(src + 4);
    *(bf16x8*)&Lt[(koct * 256 + r) * 8] = cvt8(f0, f1);
  }
  __syncthreads();
  __hip_bfloat16* outb = xbt + (size_t)bid * 16384;
#pragma unroll
  for (int j = 0; j < 8; ++j) {
    int s = j * 256 + t;
    *(bf16x8*)(outb + (size_t)s * 8) = *(const bf16x8*)&Lt[s * 8];
  }
}

// wt pre-tiled, 128-col panels: col n (0..1279), k (0..511):
// elem = (n>>7)*65536 + ((k>>3)*128 + (n&127))*8 + (k&7).
__global__ __launch_bounds__(256) void transpose_w(
    const float* __restrict__ wq, const float* __restrict__ wk,
    const float* __restrict__ wv, const float* __restrict__ wo,
    __hip_bfloat16* __restrict__ wt) {
  __shared__ float tile[32][33];
  int n0 = blockIdx.x * 32, k0 = blockIdx.y * 32;
  const float* W;
  int ld, nc;
  if (n0 < 512)      { W = wq; ld = 512; nc = n0; }
  else if (n0 < 640) { W = wk; ld = 128; nc = n0 - 512; }
  else if (n0 < 768) { W = wv; ld = 128; nc = n0 - 640; }
  else               { W = wo; ld = 512; nc = n0 - 768; }
  int x = threadIdx.x & 31, y = threadIdx.x >> 5;
#pragma unroll
  for (int i = 0; i < 4; ++i)
    tile[y + 8 * i][x] = W[(size_t)(k0 + y + 8 * i) * ld + nc + x];
  __syncthreads();
#pragma unroll
  for (int i = 0; i < 4; ++i) {
    int n = n0 + y + 8 * i, k = k0 + x;
    wt[((size_t)(n >> 7) << 16) + ((size_t)((k >> 3) * 128 + (n & 127))) * 8 +
       (k & 7)] = __float2bfloat16(tile[x][y + 8 * i]);
  }
}

// 128x128 2-blocks/CU GEMM. A = xb_t (256-row tiles, use half per block).
// wt: per K-tile 8192-elem chunk at kt*8192. C row-major (N = NT*128).
template <int NT, int NB0, typename OutT>
__global__ __launch_bounds__(256, 2) void gemm2b(
    const __hip_bfloat16* __restrict__ At, const __hip_bfloat16* __restrict__ wt,
    OutT* __restrict__ C) {
  constexpr int N = NT * 128;
  __shared__ __hip_bfloat16 Al[2][8192];  // 2 x 16KB
  __shared__ __hip_bfloat16 Bd[2][8192];  // 2 x 16KB
  const int tid = threadIdx.x;
  const int lane = tid & 63;
  const int w = tid >> 6;             // 0..3
  const int wr = w >> 1, wc = w & 1;  // 2m x 2n
  constexpr int NWG = 256 * NT;
  const int ng = (blockIdx.x & 7) * (NWG / 8) + (blockIdx.x >> 3);
  const int mt = ng / NT;       // 0..255 (128-row tile)
  const int n0 = (ng % NT) * 128;
  const int m0 = mt * 128;
  const int half = mt & 1;
  const __hip_bfloat16* Abase = At + (size_t)(mt >> 1) * 8 * 16384;
  const __hip_bfloat16* Bbase = wt + ((size_t)(NB0 + ng % NT) << 16);

  const int kbq = lane >> 4, fr = lane & 15;
  f32x4 acc[4][4] = {};

  // stage K-tile kt into buf: 4 A + 4 B gloads per thread.
  auto stage = [&](int buf, int kt) {
    const __hip_bfloat16* Bs = Bbase + (size_t)kt * 8192;
#pragma unroll
    for (int j = 0; j < 4; ++j) {
      int s = j * 256 + tid;  // LDS slot kg*128+row, kg=s>>7, row=s&127
      int srcslot = ((s >> 7) << 8) + half * 128 + (s & 127);
      gload_lds16(Abase + (size_t)kt * 16384 + (size_t)srcslot * 8,
                  &Al[buf][(j * 256 + w * 64) * 8]);
    }
#pragma unroll
    for (int j = 0; j < 4; ++j) {
      int s = j * 256 + tid;
      gload_lds16(Bs + (size_t)s * 8, &Bd[buf][(j * 256 + w * 64) * 8]);
    }
  };

  stage(0, 0);
  asm volatile("s_waitcnt vmcnt(0)" ::: "memory");
  __builtin_amdgcn_s_barrier();

#pragma unroll
  for (int kt = 0; kt < 8; ++kt) {
    const int cur = kt & 1;
    // ---- phase A: kg = kbq (0..3). No manual lgkm pin: compiler emits
    // fine-grained lgkmcnt and may pipeline phase-B reads under these MFMAs.
    {
      bf16x8 a[4], b[4];
#pragma unroll
      for (int mi = 0; mi < 4; ++mi)
        a[mi] = *(const bf16x8*)
            &Al[cur][(kbq * 128 + wr * 64 + mi * 16 + fr) * 8];
#pragma unroll
      for (int ni = 0; ni < 4; ++ni)
        b[ni] = *(const bf16x8*)
            &Bd[cur][(kbq * 128 + wc * 64 + ni * 16 + fr) * 8];
      if (kt < 7) stage(cur ^ 1, kt + 1);
      __builtin_amdgcn_s_setprio(1);
#pragma unroll
      for (int mi = 0; mi < 4; ++mi)
#pragma unroll
        for (int ni = 0; ni < 4; ++ni)
          acc[mi][ni] = __builtin_amdgcn_mfma_f32_16x16x32_bf16(
              a[mi], b[ni], acc[mi][ni], 0, 0, 0);
      __builtin_amdgcn_s_setprio(0);
    }
    // ---- phase B: kg = 4 + kbq
    {
      bf16x8 a[4], b[4];
      const int kg = 4 + kbq;
#pragma unroll
      for (int mi = 0; mi < 4; ++mi)
        a[mi] = *(const bf16x8*)
            &Al[cur][(kg * 128 + wr * 64 + mi * 16 + fr) * 8];
#pragma unroll
      for (int ni = 0; ni < 4; ++ni)
        b[ni] = *(const bf16x8*)
            &Bd[cur][(kg * 128 + wc * 64 + ni * 16 + fr) * 8];
      __builtin_amdgcn_s_setprio(1);
#pragma unroll
      for (int mi = 0; mi < 4; ++mi)
#pragma unroll
        for (int ni = 0; ni < 4; ++ni)
          acc[mi][ni] = __builtin_amdgcn_mfma_f32_16x16x32_bf16(
              a[mi], b[ni], acc[mi][ni], 0, 0, 0);
      __builtin_amdgcn_s_setprio(0);
    }
    if (kt < 7) {
      asm volatile("s_waitcnt vmcnt(0)" ::: "memory");  // stage(kt+1) landed
      __builtin_amdgcn_s_barrier();  // all waves done reading buf cur
    }
  }

  // C/D layout: col=lane&15, row=(lane>>4)*4+reg  [m89]
#pragma unroll
  for (int mi = 0; mi < 4; ++mi) {
#pragma unroll
    for (int ni = 0; ni < 4; ++ni) {
      int col = n0 + wc * 64 + ni * 16 + (lane & 15);
#pragma unroll
      for (int r = 0; r < 4; ++r) {
        int row = m0 + wr * 64 + mi * 16 + (lane >> 4) * 4 + r;
        if constexpr (sizeof(OutT) == 2)
          C[(size_t)row * N + col] = __float2bfloat16(acc[mi][ni][r]);
        else
          C[(size_t)row * N + col] = acc[mi][ni][r];
      }
    }
  }
}

// Persistent-B register-streaming GEMM (r13 structure) for the out-proj.
template <int NT, int NB0, int MI, bool DEEP, typename OutT>
__global__ __launch_bounds__(512, 2) void gemm_persist(
    const __hip_bfloat16* __restrict__ A, const __hip_bfloat16* __restrict__ wt,
    OutT* __restrict__ C) {
  constexpr int N = NT * 128;
  constexpr int MT = MI * 128;
  __shared__ __hip_bfloat16 Bl[65536];
  const int tid = threadIdx.x;
  const int lane = tid & 63;
  const int w = tid >> 6;
  constexpr int NWG = (M_TOT / MT) * NT;
  const int ng = (blockIdx.x & 7) * (NWG / 8) + (blockIdx.x >> 3);
  const int m0 = (ng / NT) * MT;
  const int n0 = (ng % NT) * 128;

  {
    const __hip_bfloat16* Bblk = wt + ((size_t)(NB0 + ng % NT) << 16);
#pragma unroll
    for (int j = 0; j < 16; ++j)
      gload_lds16(Bblk + (size_t)(j * 512 + w * 64 + lane) * 8,
                  &Bl[(j * 512 + w * 64) * 8]);
  }

  const int kbq = lane >> 4, fr = lane & 15;
  const __hip_bfloat16* pA =
      A + (size_t)(m0 + w * MI * 16 + fr) * 512 + kbq * 8;

  f32x4 acc[MI][8] = {};
  constexpr int AR = DEEP ? 3 : 2;
  bf16x8 a[AR][MI], b[2][8];

#pragma unroll
  for (int mi = 0; mi < MI; ++mi)
    a[0][mi] = *(const bf16x8*)(pA + mi * 16 * 512);
  if constexpr (DEEP) {
#pragma unroll
    for (int mi = 0; mi < MI; ++mi)
      a[1][mi] = *(const bf16x8*)(pA + mi * 16 * 512 + 32);
  }
  __builtin_amdgcn_sched_barrier(0);
  asm volatile("s_waitcnt vmcnt(4)" ::: "memory");
  __syncthreads();

#pragma unroll
  for (int ni = 0; ni < 8; ++ni)
    b[0][ni] = *(const bf16x8*)&Bl[(kbq * 128 + ni * 16 + fr) * 8];

#pragma unroll
  for (int ks = 0; ks < 16; ++ks) {
    const int cur = ks & 1;
    if constexpr (DEEP) {
      if (ks + 2 < 16) {
#pragma unroll
        for (int mi = 0; mi < MI; ++mi)
          a[(ks + 2) % 3][mi] =
              *(const bf16x8*)(pA + mi * 16 * 512 + (ks + 2) * 32);
      }
    } else {
      if (ks + 1 < 16) {
#pragma unroll
        for (int mi = 0; mi < MI; ++mi)
          a[(ks + 1) & 1][mi] =
              *(const bf16x8*)(pA + mi * 16 * 512 + (ks + 1) * 32);
      }
    }
    if (ks + 1 < 16) {
#pragma unroll
      for (int ni = 0; ni < 8; ++ni)
        b[cur ^ 1][ni] = *(const bf16x8*)
            &Bl[(((ks + 1) * 4 + kbq) * 128 + ni * 16 + fr) * 8];
    }
    const int ai = DEEP ? (ks % 3) : cur;
    __builtin_amdgcn_s_setprio(1);
#pragma unroll
    for (int mi = 0; mi < MI; ++mi)
#pragma unroll
      for (int ni = 0; ni < 8; ++ni)
        acc[mi][ni] = __builtin_amdgcn_mfma_f32_16x16x32_bf16(
            a[ai][mi], b[cur][ni], acc[mi][ni], 0, 0, 0);
    __builtin_amdgcn_s_setprio(0);
  }

#pragma unroll
  for (int mi = 0; mi < MI; ++mi) {
#pragma unroll
    for (int ni = 0; ni < 8; ++ni) {
      int col = n0 + ni * 16 + (lane & 15);
#pragma unroll
      for (int r = 0; r < 4; ++r) {
        int row = m0 + w * MI * 16 + mi * 16 + (lane >> 4) * 4 + r;
        if constexpr (sizeof(OutT) == 2)
          C[(size_t)row * N + col] = __float2bfloat16(acc[mi][ni][r]);
        else
          C[(size_t)row * N + col] = acc[mi][ni][r];
      }
    }
  }
}

// attn: 8 lanes per position; ushort8 loads; lane-local RoPE pairs;
// 3-hop shuffle dots; 1KB-contiguous stores.
__global__ __launch_bounds__(256) void attn_heads(
    const __hip_bfloat16* __restrict__ qkv, const float* __restrict__ fcos,
    const float* __restrict__ fsin, __hip_bfloat16* __restrict__ out2) {
  const int lane = threadIdx.x & 63;
  const int wvid = blockIdx.x * 4 + (threadIdx.x >> 6);
  const int pos = lane >> 3, dlane = lane & 7;
  const int gt = wvid * 8 + pos;
  const int b = gt >> 12, t = gt & 4095;
  const size_t row = (size_t)gt * 768;

  f32x4 c4 = *(const f32x4*)&fcos[(size_t)t * 32 + dlane * 4];
  f32x4 s4 = *(const f32x4*)&fsin[(size_t)t * 32 + dlane * 4];

  float q[8][8], k[2][8], v[2][8];
#pragma unroll
  for (int h = 0; h < 8; ++h) {
    ushort8 u = *(const ushort8*)&qkv[row + h * 64 + dlane * 8];
#pragma unroll
    for (int j = 0; j < 4; ++j) {
      float xr = bf2f(u[2 * j]), xi = bf2f(u[2 * j + 1]);
      q[h][2 * j] = xr * c4[j] - xi * s4[j];
      q[h][2 * j + 1] = xr * s4[j] + xi * c4[j];
    }
  }
#pragma unroll
  for (int c = 0; c < 2; ++c) {
    ushort8 uk = *(const ushort8*)&qkv[row + 512 + c * 64 + dlane * 8];
    ushort8 uv = *(const ushort8*)&qkv[row + 640 + c * 64 + dlane * 8];
#pragma unroll
    for (int j = 0; j < 4; ++j) {
      float xr = bf2f(uk[2 * j]), xi = bf2f(uk[2 * j + 1]);
      k[c][2 * j] = xr * c4[j] - xi * s4[j];
      k[c][2 * j + 1] = xr * s4[j] + xi * c4[j];
    }
#pragma unroll
    for (int j = 0; j < 8; ++j) v[c][j] = bf2f(uv[j]);
  }

  float dot[8][2];
#pragma unroll
  for (int h = 0; h < 8; ++h)
#pragma unroll
    for (int c = 0; c < 2; ++c) {
      float p = 0.f;
#pragma unroll
      for (int j = 0; j < 8; ++j) p += q[h][j] * k[c][j];
      p += __shfl_xor(p, 1);
      p += __shfl_xor(p, 2);
      p += __shfl_xor(p, 4);
      dot[h][c] = p * 0.125f;
    }

#pragma unroll
  for (int h = 0; h < 8; ++h) {
    int c0 = (h + 1 < 4) ? (h + 1) : 4;
    int c1 = (h + 1) - c0;
    float w0, w1;
    if (c1 > 0) {
      float s0 = dot[h][0], s1 = dot[h][1];
      float m = fmaxf(s0, s1);
      float e0 = (float)c0 * expf(s0 - m), e1 = (float)c1 * expf(s1 - m);
      float inv = 1.f / (e0 + e1);
      w0 = e0 * inv;
      w1 = e1 * inv;
    } else {
      w0 = 1.f;
      w1 = 0.f;
    }
    ushort8 o;
#pragma unroll
    for (int j = 0; j < 8; ++j) {
      __hip_bfloat16 ob = __float2bfloat16(w0 * v[0][j] + w1 * v[1][j]);
      o[j] = *(unsigned short*)&ob;
    }
    *(ushort8*)&out2[((size_t)(b * 4096 + h * 512 + (t >> 3))) * 512 +
                     pos * 64 + dlane * 8] = o;
  }
}

extern "C" void kernel_launch(void* const* d_in, const int* in_sizes, int n_in,
                              void* d_out, int out_size, void* d_ws,
                              size_t ws_size, hipStream_t stream) {
  const float* x    = (const float*)d_in[0];
  const float* fcos = (const float*)d_in[1];
  const float* fsin = (const float*)d_in[2];
  const float* wq   = (const float*)d_in[3];
  const float* wk   = (const float*)d_in[4];
  const float* wv   = (const float*)d_in[5];
  const float* wo   = (const float*)d_in[6];
  float* out = (float*)d_out;

  __hip_bfloat16* xbt  = (__hip_bfloat16*)d_ws;  // 32MB (tiled)
  __hip_bfloat16* out2 = xbt;                     // alias (dead after gemm6)
  __hip_bfloat16* qkv  = (__hip_bfloat16*)((char*)d_ws + (size_t)M_TOT * 512 * 2);  // 48MB
  __hip_bfloat16* wt   = (__hip_bfloat16*)((char*)d_ws + (size_t)M_TOT * 512 * 2 +
                                           (size_t)M_TOT * 768 * 2);  // 1.31MB

  convert_x2<<<dim3(1024), 256, 0, stream>>>(x, xbt);
  transpose_w<<<dim3(1280 / 32, 512 / 32), 256, 0, stream>>>(wq, wk, wv, wo, wt);
  gemm2b<6, 0, __hip_bfloat16><<<dim3(1536), 256, 0, stream>>>(xbt, wt, qkv);
  attn_heads<<<dim3(M_TOT / 8 / 4), 256, 0, stream>>>(qkv, fcos, fsin, out2);
  gemm_persist<4, 6, 4, false, float>
      <<<dim3(256), 512, 0, stream>>>(out2, wt, out);
}

// Round 18
// 92.091 us; speedup vs baseline: 1.0820x; 1.0045x over previous
//
#include <hip/hip_runtime.h>
#include <hip/hip_bf16.h>

// B=8, S=4096, H=8, HKV=2, D=64, HID=512. M_TOT=32768, K=512.
// Pipeline:
//   K0 convert_x2   : x f32 -> xb_t bf16 tiled (mblk256, kt, kg, row)
//   K1 transpose_w  : weights -> wt bf16 (panel layout, kt-chunks contiguous)
//   K2 gemm2b<6,0>  : xb_t @ wt[0..5] -> qkv bf16 [128x128, 2 blk/CU]
//   K3 attn_heads_t : RoPE + analytic GQA -> out2t in TILED layout via a
//                     32KB LDS bounce (4 waves = 4 consecutive t-octs ->
//                     64B-contiguous tiled stores)
//   K4 gemm2b<4,6>  : out2t @ wt[6..9] -> d_out f32 [same proven structure]
// gemm2b: BM128 x BN128, BK=64 (8 K-tiles), 2-buffer LDS (64KB) -> 2
// blocks/CU (m114 cross-block overlap, r15 win). 4 waves 2m x 2n, acc[4][4].
// No manual lgkm pins (r17: compiler's fine-grained lgkmcnt is as good).
// r16 lesson: row-major per-lane A staging = 64-line gather per gload (4x L2
// traffic) -> instead emit out2 pre-tiled from attn (this round).
// Scramble (ref transpose(0,2,1,3).reshape): attnout[b,t,h,d] ->
//   out2 row R = b*4096+h*512+t/8, col c = (t%8)*64+d; tiled elem =
//   ((R>>8)*8 + (c>>6))*16384 + (((c&63)>>3)*256 + (R&255))*8 + (c&7).

#define M_TOT 32768

typedef __bf16 bf16x8 __attribute__((ext_vector_type(8)));
typedef float f32x4 __attribute__((ext_vector_type(4)));
typedef unsigned short ushort8 __attribute__((ext_vector_type(8)));

__device__ __forceinline__ void gload_lds16(const __hip_bfloat16* g,
                                            __hip_bfloat16* l) {
  __builtin_amdgcn_global_load_lds(
      (const __attribute__((address_space(1))) unsigned int*)g,
      (__attribute__((address_space(3))) unsigned int*)l, 16, 0, 0);
}

__device__ __forceinline__ float bf2f(unsigned short u) {
  union { unsigned int i; float f; } c;
  c.i = (unsigned int)u << 16;
  return c.f;
}

__device__ __forceinline__ bf16x8 cvt8(float4 a, float4 b) {
  bf16x8 r;
  r[0] = (__bf16)a.x; r[1] = (__bf16)a.y; r[2] = (__bf16)a.z; r[3] = (__bf16)a.w;
  r[4] = (__bf16)b.x; r[5] = (__bf16)b.y; r[6] = (__bf16)b.z; r[7] = (__bf16)b.w;
  return r;
}

// x (row-major f32) -> xb_t tiled bf16: tile (mblk 0..127, kt 0..7) holds
// slots (kg 0..7, row 0..255): elem((mblk*8+kt)*16384 + (kg*256+row)*8 + e)
// = x[mblk*256+row][kt*64+kg*8+e].
__global__ __launch_bounds__(256) void convert_x2(
    const float* __restrict__ x, __hip_bfloat16* __restrict__ xbt) {
  __shared__ __hip_bfloat16 Lt[16384];  // 32KB
  const int bid = blockIdx.x;           // = mblk*8 + kt
  const int mblk = bid >> 3, kt = bid & 7;
  const int t = threadIdx.x;
  const int koct = t & 7;
#pragma unroll
  for (int p = 0; p < 8; ++p) {
    int r = p * 32 + (t >> 3);
    const float* src = x + (size_t)(mblk * 256 + r) * 512 + kt * 64 + koct * 8;
    float4 f0 = *(const float4*)src;
    float4 f1 = *(const float4*)(src + 4);
    *(bf16x8*)&Lt[(koct * 256 + r) * 8] = cvt8(f0, f1);
  }
  __syncthreads();
  __hip_bfloat16* outb = xbt + (size_t)bid * 16384;
#pragma unroll
  for (int j = 0; j < 8; ++j) {
    int s = j * 256 + t;
    *(bf16x8*)(outb + (size_t)s * 8) = *(const bf16x8*)&Lt[s * 8];
  }
}

// wt pre-tiled, 128-col panels: col n (0..1279), k (0..511):
// elem = (n>>7)*65536 + ((k>>3)*128 + (n&127))*8 + (k&7).
__global__ __launch_bounds__(256) void transpose_w(
    const float* __restrict__ wq, const float* __restrict__ wk,
    const float* __restrict__ wv, const float* __restrict__ wo,
    __hip_bfloat16* __restrict__ wt) {
  __shared__ float tile[32][33];
  int n0 = blockIdx.x * 32, k0 = blockIdx.y * 32;
  const float* W;
  int ld, nc;
  if (n0 < 512)      { W = wq; ld = 512; nc = n0; }
  else if (n0 < 640) { W = wk; ld = 128; nc = n0 - 512; }
  else if (n0 < 768) { W = wv; ld = 128; nc = n0 - 640; }
  else               { W = wo; ld = 512; nc = n0 - 768; }
  int x = threadIdx.x & 31, y = threadIdx.x >> 5;
#pragma unroll
  for (int i = 0; i < 4; ++i)
    tile[y + 8 * i][x] = W[(size_t)(k0 + y + 8 * i) * ld + nc + x];
  __syncthreads();
#pragma unroll
  for (int i = 0; i < 4; ++i) {
    int n = n0 + y + 8 * i, k = k0 + x;
    wt[((size_t)(n >> 7) << 16) + ((size_t)((k >> 3) * 128 + (n & 127))) * 8 +
       (k & 7)] = __float2bfloat16(tile[x][y + 8 * i]);
  }
}

// 128x128 2-blocks/CU GEMM. A tiled (256-row tiles, use half per block).
// wt: per K-tile 8192-elem chunk at kt*8192. C row-major (N = NT*128).
template <int NT, int NB0, typename OutT>
__global__ __launch_bounds__(256, 2) void gemm2b(
    const __hip_bfloat16* __restrict__ At, const __hip_bfloat16* __restrict__ wt,
    OutT* __restrict__ C) {
  constexpr int N = NT * 128;
  __shared__ __hip_bfloat16 Al[2][8192];  // 2 x 16KB
  __shared__ __hip_bfloat16 Bd[2][8192];  // 2 x 16KB
  const int tid = threadIdx.x;
  const int lane = tid & 63;
  const int w = tid >> 6;             // 0..3
  const int wr = w >> 1, wc = w & 1;  // 2m x 2n
  constexpr int NWG = 256 * NT;
  const int ng = (blockIdx.x & 7) * (NWG / 8) + (blockIdx.x >> 3);
  const int mt = ng / NT;       // 0..255 (128-row tile)
  const int n0 = (ng % NT) * 128;
  const int m0 = mt * 128;
  const int half = mt & 1;
  const __hip_bfloat16* Abase = At + (size_t)(mt >> 1) * 8 * 16384;
  const __hip_bfloat16* Bbase = wt + ((size_t)(NB0 + ng % NT) << 16);

  const int kbq = lane >> 4, fr = lane & 15;
  f32x4 acc[4][4] = {};

  // stage K-tile kt into buf: 4 A + 4 B gloads per thread.
  auto stage = [&](int buf, int kt) {
    const __hip_bfloat16* Bs = Bbase + (size_t)kt * 8192;
#pragma unroll
    for (int j = 0; j < 4; ++j) {
      int s = j * 256 + tid;  // LDS slot kg*128+row, kg=s>>7, row=s&127
      int srcslot = ((s >> 7) << 8) + half * 128 + (s & 127);
      gload_lds16(Abase + (size_t)kt * 16384 + (size_t)srcslot * 8,
                  &Al[buf][(j * 256 + w * 64) * 8]);
    }
#pragma unroll
    for (int j = 0; j < 4; ++j) {
      int s = j * 256 + tid;
      gload_lds16(Bs + (size_t)s * 8, &Bd[buf][(j * 256 + w * 64) * 8]);
    }
  };

  stage(0, 0);
  asm volatile("s_waitcnt vmcnt(0)" ::: "memory");
  __builtin_amdgcn_s_barrier();

#pragma unroll
  for (int kt = 0; kt < 8; ++kt) {
    const int cur = kt & 1;
    // ---- phase A: kg = kbq (0..3)
    {
      bf16x8 a[4], b[4];
#pragma unroll
      for (int mi = 0; mi < 4; ++mi)
        a[mi] = *(const bf16x8*)
            &Al[cur][(kbq * 128 + wr * 64 + mi * 16 + fr) * 8];
#pragma unroll
      for (int ni = 0; ni < 4; ++ni)
        b[ni] = *(const bf16x8*)
            &Bd[cur][(kbq * 128 + wc * 64 + ni * 16 + fr) * 8];
      if (kt < 7) stage(cur ^ 1, kt + 1);
      __builtin_amdgcn_s_setprio(1);
#pragma unroll
      for (int mi = 0; mi < 4; ++mi)
#pragma unroll
        for (int ni = 0; ni < 4; ++ni)
          acc[mi][ni] = __builtin_amdgcn_mfma_f32_16x16x32_bf16(
              a[mi], b[ni], acc[mi][ni], 0, 0, 0);
      __builtin_amdgcn_s_setprio(0);
    }
    // ---- phase B: kg = 4 + kbq
    {
      bf16x8 a[4], b[4];
      const int kg = 4 + kbq;
#pragma unroll
      for (int mi = 0; mi < 4; ++mi)
        a[mi] = *(const bf16x8*)
            &Al[cur][(kg * 128 + wr * 64 + mi * 16 + fr) * 8];
#pragma unroll
      for (int ni = 0; ni < 4; ++ni)
        b[ni] = *(const bf16x8*)
            &Bd[cur][(kg * 128 + wc * 64 + ni * 16 + fr) * 8];
      __builtin_amdgcn_s_setprio(1);
#pragma unroll
      for (int mi = 0; mi < 4; ++mi)
#pragma unroll
        for (int ni = 0; ni < 4; ++ni)
          acc[mi][ni] = __builtin_amdgcn_mfma_f32_16x16x32_bf16(
              a[mi], b[ni], acc[mi][ni], 0, 0, 0);
      __builtin_amdgcn_s_setprio(0);
    }
    if (kt < 7) {
      asm volatile("s_waitcnt vmcnt(0)" ::: "memory");  // stage(kt+1) landed
      __builtin_amdgcn_s_barrier();  // all waves done reading buf cur
    }
  }

  // C/D layout: col=lane&15, row=(lane>>4)*4+reg  [m89]
#pragma unroll
  for (int mi = 0; mi < 4; ++mi) {
#pragma unroll
    for (int ni = 0; ni < 4; ++ni) {
      int col = n0 + wc * 64 + ni * 16 + (lane & 15);
#pragma unroll
      for (int r = 0; r < 4; ++r) {
        int row = m0 + wr * 64 + mi * 16 + (lane >> 4) * 4 + r;
        if constexpr (sizeof(OutT) == 2)
          C[(size_t)row * N + col] = __float2bfloat16(acc[mi][ni][r]);
        else
          C[(size_t)row * N + col] = acc[mi][ni][r];
      }
    }
  }
}

// attn with TILED output: block = 4 waves = 4 consecutive t-octs. Compute
// phase identical to before (8 lanes/position, lane-local RoPE, 3-hop
// shuffle dots); outputs bounce through padded LDS (idx' = idx + idx/8,
// 36KB) then re-emit in xbt-tiled layout as 64B-contiguous runs (4
// consecutive rows per (h, kt=sub, kg=dlane) slot group).
__global__ __launch_bounds__(256) void attn_heads_t(
    const __hip_bfloat16* __restrict__ qkv, const float* __restrict__ fcos,
    const float* __restrict__ fsin, __hip_bfloat16* __restrict__ out2t) {
  __shared__ __hip_bfloat16 Ob[2304 * 8];  // 36KB padded
  const int lane = threadIdx.x & 63;
  const int w = threadIdx.x >> 6;
  const int wvid = blockIdx.x * 4 + w;  // = t-oct global index
  const int sub = lane >> 3, dlane = lane & 7;
  const int gt = wvid * 8 + sub;
  const int t = gt & 4095;
  const size_t row = (size_t)gt * 768;

  f32x4 c4 = *(const f32x4*)&fcos[(size_t)t * 32 + dlane * 4];
  f32x4 s4 = *(const f32x4*)&fsin[(size_t)t * 32 + dlane * 4];

  float q[8][8], k[2][8], v[2][8];
#pragma unroll
  for (int h = 0; h < 8; ++h) {
    ushort8 u = *(const ushort8*)&qkv[row + h * 64 + dlane * 8];
#pragma unroll
    for (int j = 0; j < 4; ++j) {
      float xr = bf2f(u[2 * j]), xi = bf2f(u[2 * j + 1]);
      q[h][2 * j] = xr * c4[j] - xi * s4[j];
      q[h][2 * j + 1] = xr * s4[j] + xi * c4[j];
    }
  }
#pragma unroll
  for (int c = 0; c < 2; ++c) {
    ushort8 uk = *(const ushort8*)&qkv[row + 512 + c * 64 + dlane * 8];
    ushort8 uv = *(const ushort8*)&qkv[row + 640 + c * 64 + dlane * 8];
#pragma unroll
    for (int j = 0; j < 4; ++j) {
      float xr = bf2f(uk[2 * j]), xi = bf2f(uk[2 * j + 1]);
      k[c][2 * j] = xr * c4[j] - xi * s4[j];
      k[c][2 * j + 1] = xr * s4[j] + xi * c4[j];
    }
#pragma unroll
    for (int j = 0; j < 8; ++j) v[c][j] = bf2f(uv[j]);
  }

  float dot[8][2];
#pragma unroll
  for (int h = 0; h < 8; ++h)
#pragma unroll
    for (int c = 0; c < 2; ++c) {
      float p = 0.f;
#pragma unroll
      for (int j = 0; j < 8; ++j) p += q[h][j] * k[c][j];
      p += __shfl_xor(p, 1);
      p += __shfl_xor(p, 2);
      p += __shfl_xor(p, 4);
      dot[h][c] = p * 0.125f;  // 1/sqrt(64)
    }

#pragma unroll
  for (int h = 0; h < 8; ++h) {
    int c0 = (h + 1 < 4) ? (h + 1) : 4;
    int c1 = (h + 1) - c0;
    float w0, w1;
    if (c1 > 0) {
      float s0 = dot[h][0], s1 = dot[h][1];
      float m = fmaxf(s0, s1);
      float e0 = (float)c0 * expf(s0 - m), e1 = (float)c1 * expf(s1 - m);
      float inv = 1.f / (e0 + e1);
      w0 = e0 * inv;
      w1 = e1 * inv;
    } else {
      w0 = 1.f;
      w1 = 0.f;
    }
    bf16x8 o;
#pragma unroll
    for (int j = 0; j < 8; ++j)
      o[j] = (__bf16)(w0 * v[0][j] + w1 * v[1][j]);
    int idx = ((w * 8 + h) * 8 + sub) * 8 + dlane;
    *(bf16x8*)&Ob[(idx + (idx >> 3)) * 8] = o;
  }

  __syncthreads();

  // store phase: thread = (h2, sub2, oi); loop dlane. 4 consecutive rows
  // (oi) -> 64B-contiguous tiled runs.
  const int b = blockIdx.x >> 7;            // 1024 blocks = 8 batches
  const int wbase = (blockIdx.x * 4) & 511; // t-oct base within batch
  const int h2 = threadIdx.x >> 5;
  const int sub2 = (threadIdx.x >> 2) & 7;
  const int oi = threadIdx.x & 3;
  const int R = b * 4096 + h2 * 512 + wbase + oi;
  const size_t dbase = ((size_t)((R >> 8) * 8 + sub2)) * 2048 + (R & 255);
#pragma unroll
  for (int dl = 0; dl < 8; ++dl) {
    int idx = ((oi * 8 + h2) * 8 + sub2) * 8 + dl;
    *(bf16x8*)&out2t[(dbase + dl * 256) * 8] =
        *(const bf16x8*)&Ob[(idx + (idx >> 3)) * 8];
  }
}

extern "C" void kernel_launch(void* const* d_in, const int* in_sizes, int n_in,
                              void* d_out, int out_size, void* d_ws,
                              size_t ws_size, hipStream_t stream) {
  const float* x    = (const float*)d_in[0];
  const float* fcos = (const float*)d_in[1];
  const float* fsin = (const float*)d_in[2];
  const float* wq   = (const float*)d_in[3];
  const float* wk   = (const float*)d_in[4];
  const float* wv   = (const float*)d_in[5];
  const float* wo   = (const float*)d_in[6];
  float* out = (float*)d_out;

  __hip_bfloat16* xbt   = (__hip_bfloat16*)d_ws;  // 32MB (tiled)
  __hip_bfloat16* out2t = xbt;                     // alias (dead after gemm6)
  __hip_bfloat16* qkv   = (__hip_bfloat16*)((char*)d_ws + (size_t)M_TOT * 512 * 2);  // 48MB
  __hip_bfloat16* wt    = (__hip_bfloat16*)((char*)d_ws + (size_t)M_TOT * 512 * 2 +
                                            (size_t)M_TOT * 768 * 2);  // 1.31MB

  convert_x2<<<dim3(1024), 256, 0, stream>>>(x, xbt);
  transpose_w<<<dim3(1280 / 32, 512 / 32), 256, 0, stream>>>(wq, wk, wv, wo, wt);
  gemm2b<6, 0, __hip_bfloat16><<<dim3(1536), 256, 0, stream>>>(xbt, wt, qkv);
  attn_heads_t<<<dim3(M_TOT / 8 / 4), 256, 0, stream>>>(qkv, fcos, fsin, out2t);
  gemm2b<4, 6, float><<<dim3(1024), 256, 0, stream>>>(out2t, wt, out);
}

// Round 19
// 90.770 us; speedup vs baseline: 1.0977x; 1.0145x over previous
//
#include <hip/hip_runtime.h>
#include <hip/hip_bf16.h>

// B=8, S=4096, H=8, HKV=2, D=64, HID=512. M_TOT=32768, K=512.
// Pipeline:
//   K0 convert_x2   : x f32 -> xb_t bf16 tiled (mblk256, kt64, kg, row)
//   K1 transpose_w  : weights -> wt bf16 (panel layout, kt-chunks contiguous)
//   K2 gemm4b<6,0>  : xb_t @ wt[0..5] -> qkv bf16 [128x128, BK=32, 4+ blk/CU]
//   K3 attn_heads_t : RoPE + analytic GQA -> out2t (tiled, via LDS bounce)
//   K4 gemm4b<4,6>  : out2t @ wt[6..9] -> d_out f32
// gemm4b (r19): BM128 x BN128, BK=32 (16 K-tiles), 2-buffer LDS = 32KB
// -> 4-5 blocks/CU (vs r15's 2). Same read:MFMA ratio as gemm2b; the
// extra co-resident blocks cover each block's per-tile vmcnt/barrier stall
// (r15 showed 2-block stagger = +7us; r18 model: 55% of gemm time is still
// stall at 2 blocks/CU). 4 waves 2m x 2n, acc[4][4], VGPR ~88 < 128 cap
// of launch_bounds(256,4) (r11 spill lesson respected).
// Per K-tile: {ds_read a[4],b[4]; stage(kt+1) 2A+2B gloads; 16 MFMA;
// vmcnt(0); barrier}. Stage stall covered by other blocks, not depth.
// Scramble (ref transpose(0,2,1,3).reshape): attnout[b,t,h,d] ->
//   out2 row R = b*4096+h*512+t/8, col c = (t%8)*64+d; tiled elem =
//   ((R>>8)*8 + (c>>6))*16384 + (((c&63)>>3)*256 + (R&255))*8 + (c&7).

#define M_TOT 32768

typedef __bf16 bf16x8 __attribute__((ext_vector_type(8)));
typedef float f32x4 __attribute__((ext_vector_type(4)));
typedef unsigned short ushort8 __attribute__((ext_vector_type(8)));

__device__ __forceinline__ void gload_lds16(const __hip_bfloat16* g,
                                            __hip_bfloat16* l) {
  __builtin_amdgcn_global_load_lds(
      (const __attribute__((address_space(1))) unsigned int*)g,
      (__attribute__((address_space(3))) unsigned int*)l, 16, 0, 0);
}

__device__ __forceinline__ float bf2f(unsigned short u) {
  union { unsigned int i; float f; } c;
  c.i = (unsigned int)u << 16;
  return c.f;
}

__device__ __forceinline__ bf16x8 cvt8(float4 a, float4 b) {
  bf16x8 r;
  r[0] = (__bf16)a.x; r[1] = (__bf16)a.y; r[2] = (__bf16)a.z; r[3] = (__bf16)a.w;
  r[4] = (__bf16)b.x; r[5] = (__bf16)b.y; r[6] = (__bf16)b.z; r[7] = (__bf16)b.w;
  return r;
}

// x (row-major f32) -> xb_t tiled bf16: tile (mblk 0..127, kt 0..7) holds
// slots (kg 0..7, row 0..255): elem((mblk*8+kt)*16384 + (kg*256+row)*8 + e)
// = x[mblk*256+row][kt*64+kg*8+e].
__global__ __launch_bounds__(256) void convert_x2(
    const float* __restrict__ x, __hip_bfloat16* __restrict__ xbt) {
  __shared__ __hip_bfloat16 Lt[16384];  // 32KB
  const int bid = blockIdx.x;           // = mblk*8 + kt
  const int mblk = bid >> 3, kt = bid & 7;
  const int t = threadIdx.x;
  const int koct = t & 7;
#pragma unroll
  for (int p = 0; p < 8; ++p) {
    int r = p * 32 + (t >> 3);
    const float* src = x + (size_t)(mblk * 256 + r) * 512 + kt * 64 + koct * 8;
    float4 f0 = *(const float4*)src;
    float4 f1 = *(const float4*)(src + 4);
    *(bf16x8*)&Lt[(koct * 256 + r) * 8] = cvt8(f0, f1);
  }
  __syncthreads();
  __hip_bfloat16* outb = xbt + (size_t)bid * 16384;
#pragma unroll
  for (int j = 0; j < 8; ++j) {
    int s = j * 256 + t;
    *(bf16x8*)(outb + (size_t)s * 8) = *(const bf16x8*)&Lt[s * 8];
  }
}

// wt pre-tiled, 128-col panels: col n (0..1279), k (0..511):
// elem = (n>>7)*65536 + ((k>>3)*128 + (n&127))*8 + (k&7).
__global__ __launch_bounds__(256) void transpose_w(
    const float* __restrict__ wq, const float* __restrict__ wk,
    const float* __restrict__ wv, const float* __restrict__ wo,
    __hip_bfloat16* __restrict__ wt) {
  __shared__ float tile[32][33];
  int n0 = blockIdx.x * 32, k0 = blockIdx.y * 32;
  const float* W;
  int ld, nc;
  if (n0 < 512)      { W = wq; ld = 512; nc = n0; }
  else if (n0 < 640) { W = wk; ld = 128; nc = n0 - 512; }
  else if (n0 < 768) { W = wv; ld = 128; nc = n0 - 640; }
  else               { W = wo; ld = 512; nc = n0 - 768; }
  int x = threadIdx.x & 31, y = threadIdx.x >> 5;
#pragma unroll
  for (int i = 0; i < 4; ++i)
    tile[y + 8 * i][x] = W[(size_t)(k0 + y + 8 * i) * ld + nc + x];
  __syncthreads();
#pragma unroll
  for (int i = 0; i < 4; ++i) {
    int n = n0 + y + 8 * i, k = k0 + x;
    wt[((size_t)(n >> 7) << 16) + ((size_t)((k >> 3) * 128 + (n & 127))) * 8 +
       (k & 7)] = __float2bfloat16(tile[x][y + 8 * i]);
  }
}

// 128x128, BK=32, 32KB-LDS GEMM (4-5 blocks/CU). A tiled xbt-style
// (256-row mblk tiles, kt64-chunked; block uses half=mt&1). wt: per-kt64
// 8192-elem chunk. C row-major (N = NT*128).
template <int NT, int NB0, typename OutT>
__global__ __launch_bounds__(256, 4) void gemm4b(
    const __hip_bfloat16* __restrict__ At, const __hip_bfloat16* __restrict__ wt,
    OutT* __restrict__ C) {
  constexpr int N = NT * 128;
  __shared__ __hip_bfloat16 Al[2][4096];  // 2 x 8KB
  __shared__ __hip_bfloat16 Bd[2][4096];  // 2 x 8KB
  const int tid = threadIdx.x;
  const int lane = tid & 63;
  const int w = tid >> 6;             // 0..3
  const int wr = w >> 1, wc = w & 1;  // 2m x 2n
  constexpr int NWG = 256 * NT;
  const int ng = (blockIdx.x & 7) * (NWG / 8) + (blockIdx.x >> 3);
  const int mt = ng / NT;       // 0..255 (128-row tile)
  const int n0 = (ng % NT) * 128;
  const int m0 = mt * 128;
  const int half = mt & 1;
  const __hip_bfloat16* Abase = At + (size_t)(mt >> 1) * 8 * 16384;
  const __hip_bfloat16* Bbase = wt + ((size_t)(NB0 + ng % NT) << 16);

  const int kbq = lane >> 4, fr = lane & 15;
  f32x4 acc[4][4] = {};

  // stage K-tile kt32 into buf: 2 A + 2 B gloads per thread.
  // kt32 = kt64*2 + khalf; kg_global = khalf*4 + kg32.
  auto stage = [&](int buf, int kt32) {
    const int kt64 = kt32 >> 1, kgo = (kt32 & 1) * 4;
    const __hip_bfloat16* As = Abase + (size_t)kt64 * 16384;
    const __hip_bfloat16* Bs = Bbase + (size_t)kt64 * 8192;
#pragma unroll
    for (int j = 0; j < 2; ++j) {
      int flat = j * 256 + tid;  // 0..511: kg=flat>>7, row128=flat&127
      int srcslot = (kgo + (flat >> 7)) * 256 + half * 128 + (flat & 127);
      gload_lds16(As + (size_t)srcslot * 8,
                  &Al[buf][(j * 256 + w * 64) * 8]);
    }
#pragma unroll
    for (int j = 0; j < 2; ++j) {
      int flat = j * 256 + tid;  // kg=flat>>7, col=flat&127
      int srcslot = (kgo + (flat >> 7)) * 128 + (flat & 127);
      gload_lds16(Bs + (size_t)srcslot * 8,
                  &Bd[buf][(j * 256 + w * 64) * 8]);
    }
  };

  stage(0, 0);
  asm volatile("s_waitcnt vmcnt(0)" ::: "memory");
  __builtin_amdgcn_s_barrier();

#pragma unroll
  for (int kt = 0; kt < 16; ++kt) {
    const int cur = kt & 1;
    bf16x8 a[4], b[4];
#pragma unroll
    for (int mi = 0; mi < 4; ++mi)
      a[mi] = *(const bf16x8*)
          &Al[cur][(kbq * 128 + wr * 64 + mi * 16 + fr) * 8];
#pragma unroll
    for (int ni = 0; ni < 4; ++ni)
      b[ni] = *(const bf16x8*)
          &Bd[cur][(kbq * 128 + wc * 64 + ni * 16 + fr) * 8];
    if (kt < 15) stage(cur ^ 1, kt + 1);
    __builtin_amdgcn_s_setprio(1);
#pragma unroll
    for (int mi = 0; mi < 4; ++mi)
#pragma unroll
      for (int ni = 0; ni < 4; ++ni)
        acc[mi][ni] = __builtin_amdgcn_mfma_f32_16x16x32_bf16(
            a[mi], b[ni], acc[mi][ni], 0, 0, 0);
    __builtin_amdgcn_s_setprio(0);
    if (kt < 15) {
      asm volatile("s_waitcnt vmcnt(0)" ::: "memory");  // stage(kt+1) landed
      __builtin_amdgcn_s_barrier();  // all waves done reading buf cur
    }
  }

  // C/D layout: col=lane&15, row=(lane>>4)*4+reg  [m89]
#pragma unroll
  for (int mi = 0; mi < 4; ++mi) {
#pragma unroll
    for (int ni = 0; ni < 4; ++ni) {
      int col = n0 + wc * 64 + ni * 16 + (lane & 15);
#pragma unroll
      for (int r = 0; r < 4; ++r) {
        int row = m0 + wr * 64 + mi * 16 + (lane >> 4) * 4 + r;
        if constexpr (sizeof(OutT) == 2)
          C[(size_t)row * N + col] = __float2bfloat16(acc[mi][ni][r]);
        else
          C[(size_t)row * N + col] = acc[mi][ni][r];
      }
    }
  }
}

// attn with TILED output: block = 4 waves = 4 consecutive t-octs. Outputs
// bounce through padded LDS (idx' = idx + idx/8) then re-emit in xbt-tiled
// layout as 64B-contiguous runs.
__global__ __launch_bounds__(256) void attn_heads_t(
    const __hip_bfloat16* __restrict__ qkv, const float* __restrict__ fcos,
    const float* __restrict__ fsin, __hip_bfloat16* __restrict__ out2t) {
  __shared__ __hip_bfloat16 Ob[2304 * 8];  // 36KB padded
  const int lane = threadIdx.x & 63;
  const int w = threadIdx.x >> 6;
  const int wvid = blockIdx.x * 4 + w;  // = t-oct global index
  const int sub = lane >> 3, dlane = lane & 7;
  const int gt = wvid * 8 + sub;
  const int t = gt & 4095;
  const size_t row = (size_t)gt * 768;

  f32x4 c4 = *(const f32x4*)&fcos[(size_t)t * 32 + dlane * 4];
  f32x4 s4 = *(const f32x4*)&fsin[(size_t)t * 32 + dlane * 4];

  float q[8][8], k[2][8], v[2][8];
#pragma unroll
  for (int h = 0; h < 8; ++h) {
    ushort8 u = *(const ushort8*)&qkv[row + h * 64 + dlane * 8];
#pragma unroll
    for (int j = 0; j < 4; ++j) {
      float xr = bf2f(u[2 * j]), xi = bf2f(u[2 * j + 1]);
      q[h][2 * j] = xr * c4[j] - xi * s4[j];
      q[h][2 * j + 1] = xr * s4[j] + xi * c4[j];
    }
  }
#pragma unroll
  for (int c = 0; c < 2; ++c) {
    ushort8 uk = *(const ushort8*)&qkv[row + 512 + c * 64 + dlane * 8];
    ushort8 uv = *(const ushort8*)&qkv[row + 640 + c * 64 + dlane * 8];
#pragma unroll
    for (int j = 0; j < 4; ++j) {
      float xr = bf2f(uk[2 * j]), xi = bf2f(uk[2 * j + 1]);
      k[c][2 * j] = xr * c4[j] - xi * s4[j];
      k[c][2 * j + 1] = xr * s4[j] + xi * c4[j];
    }
#pragma unroll
    for (int j = 0; j < 8; ++j) v[c][j] = bf2f(uv[j]);
  }

  float dot[8][2];
#pragma unroll
  for (int h = 0; h < 8; ++h)
#pragma unroll
    for (int c = 0; c < 2; ++c) {
      float p = 0.f;
#pragma unroll
      for (int j = 0; j < 8; ++j) p += q[h][j] * k[c][j];
      p += __shfl_xor(p, 1);
      p += __shfl_xor(p, 2);
      p += __shfl_xor(p, 4);
      dot[h][c] = p * 0.125f;  // 1/sqrt(64)
    }

#pragma unroll
  for (int h = 0; h < 8; ++h) {
    int c0 = (h + 1 < 4) ? (h + 1) : 4;
    int c1 = (h + 1) - c0;
    float w0, w1;
    if (c1 > 0) {
      float s0 = dot[h][0], s1 = dot[h][1];
      float m = fmaxf(s0, s1);
      float e0 = (float)c0 * expf(s0 - m), e1 = (float)c1 * expf(s1 - m);
      float inv = 1.f / (e0 + e1);
      w0 = e0 * inv;
      w1 = e1 * inv;
    } else {
      w0 = 1.f;
      w1 = 0.f;
    }
    bf16x8 o;
#pragma unroll
    for (int j = 0; j < 8; ++j)
      o[j] = (__bf16)(w0 * v[0][j] + w1 * v[1][j]);
    int idx = ((w * 8 + h) * 8 + sub) * 8 + dlane;
    *(bf16x8*)&Ob[(idx + (idx >> 3)) * 8] = o;
  }

  __syncthreads();

  // store phase: thread = (h2, sub2, oi); loop dlane. 4 consecutive rows
  // (oi) -> 64B-contiguous tiled runs.
  const int b = blockIdx.x >> 7;            // 1024 blocks = 8 batches
  const int wbase = (blockIdx.x * 4) & 511; // t-oct base within batch
  const int h2 = threadIdx.x >> 5;
  const int sub2 = (threadIdx.x >> 2) & 7;
  const int oi = threadIdx.x & 3;
  const int R = b * 4096 + h2 * 512 + wbase + oi;
  const size_t dbase = ((size_t)((R >> 8) * 8 + sub2)) * 2048 + (R & 255);
#pragma unroll
  for (int dl = 0; dl < 8; ++dl) {
    int idx = ((oi * 8 + h2) * 8 + sub2) * 8 + dl;
    *(bf16x8*)&out2t[(dbase + dl * 256) * 8] =
        *(const bf16x8*)&Ob[(idx + (idx >> 3)) * 8];
  }
}

extern "C" void kernel_launch(void* const* d_in, const int* in_sizes, int n_in,
                              void* d_out, int out_size, void* d_ws,
                              size_t ws_size, hipStream_t stream) {
  const float* x    = (const float*)d_in[0];
  const float* fcos = (const float*)d_in[1];
  const float* fsin = (const float*)d_in[2];
  const float* wq   = (const float*)d_in[3];
  const float* wk   = (const float*)d_in[4];
  const float* wv   = (const float*)d_in[5];
  const float* wo   = (const float*)d_in[6];
  float* out = (float*)d_out;

  __hip_bfloat16* xbt   = (__hip_bfloat16*)d_ws;  // 32MB (tiled)
  __hip_bfloat16* out2t = xbt;                     // alias (dead after gemm6)
  __hip_bfloat16* qkv   = (__hip_bfloat16*)((char*)d_ws + (size_t)M_TOT * 512 * 2);  // 48MB
  __hip_bfloat16* wt    = (__hip_bfloat16*)((char*)d_ws + (size_t)M_TOT * 512 * 2 +
                                            (size_t)M_TOT * 768 * 2);  // 1.31MB

  convert_x2<<<dim3(1024), 256, 0, stream>>>(x, xbt);
  transpose_w<<<dim3(1280 / 32, 512 / 32), 256, 0, stream>>>(wq, wk, wv, wo, wt);
  gemm4b<6, 0, __hip_bfloat16><<<dim3(1536), 256, 0, stream>>>(xbt, wt, qkv);
  attn_heads_t<<<dim3(M_TOT / 8 / 4), 256, 0, stream>>>(qkv, fcos, fsin, out2t);
  gemm4b<4, 6, float><<<dim3(1024), 256, 0, stream>>>(out2t, wt, out);
}

// Round 20
// 90.551 us; speedup vs baseline: 1.1004x; 1.0024x over previous
//
#include <hip/hip_runtime.h>
#include <hip/hip_bf16.h>

// B=8, S=4096, H=8, HKV=2, D=64, HID=512. M_TOT=32768, K=512.
// Pipeline:
//   K0 prep         : [blocks 0..1023] x f32 -> xb_t bf16 tiled; [1024..1663]
//                     weights -> wt bf16 (merged dispatch, saves a launch gap)
//   K1 gemm_wide<3,0> : xb_t @ wt[0..5] -> qkv bf16  [128x256, BK=32]
//   K2 attn_heads_t : RoPE + analytic GQA -> out2t (tiled, via LDS bounce)
//   K3 gemm_wide<2,6> : out2t @ wt[6..9] -> d_out f32
// gemm_wide (r20): BM128 x BN256, BK=32 (16 K-tiles), 2-buffer LDS 48KB,
// 4 waves of 64x128 (acc[4][8]) -> LDS bytes/FLOP -26% vs 64x64 waves
// (r19 post-mortem: GEMMs are ~60%-of-LDS-BW bound; wave-tile ratio is the
// remaining lever, not occupancy). VGPR ~190 -> launch_bounds(256,2)
// (budget 256 >= footprint; prevents 3/SIMD spill attempt — r11 lesson).
// 2 blocks/CU = proven r15 stagger regime. Per K-tile: {ds_read a[4],b[8];
// stage(kt+1) 2A+4B gloads; 32 MFMA; vmcnt(0); barrier}.
// Scramble (ref transpose(0,2,1,3).reshape): attnout[b,t,h,d] ->
//   out2 row R = b*4096+h*512+t/8, col c = (t%8)*64+d; tiled elem =
//   ((R>>8)*8 + (c>>6))*16384 + (((c&63)>>3)*256 + (R&255))*8 + (c&7).

#define M_TOT 32768

typedef __bf16 bf16x8 __attribute__((ext_vector_type(8)));
typedef float f32x4 __attribute__((ext_vector_type(4)));
typedef unsigned short ushort8 __attribute__((ext_vector_type(8)));

__device__ __forceinline__ void gload_lds16(const __hip_bfloat16* g,
                                            __hip_bfloat16* l) {
  __builtin_amdgcn_global_load_lds(
      (const __attribute__((address_space(1))) unsigned int*)g,
      (__attribute__((address_space(3))) unsigned int*)l, 16, 0, 0);
}

__device__ __forceinline__ float bf2f(unsigned short u) {
  union { unsigned int i; float f; } c;
  c.i = (unsigned int)u << 16;
  return c.f;
}

__device__ __forceinline__ bf16x8 cvt8(float4 a, float4 b) {
  bf16x8 r;
  r[0] = (__bf16)a.x; r[1] = (__bf16)a.y; r[2] = (__bf16)a.z; r[3] = (__bf16)a.w;
  r[4] = (__bf16)b.x; r[5] = (__bf16)b.y; r[6] = (__bf16)b.z; r[7] = (__bf16)b.w;
  return r;
}

// Merged prep: blocks 0..1023 convert x -> xbt (tiled); blocks 1024..1663
// transpose weights -> wt (128-col panels, kt64-chunked).
// xbt: tile (mblk 0..127, kt 0..7) slots (kg 0..7, row 0..255):
//   elem((mblk*8+kt)*16384 + (kg*256+row)*8 + e) = x[mblk*256+row][kt*64+kg*8+e]
// wt: elem = (n>>7)*65536 + ((k>>3)*128 + (n&127))*8 + (k&7).
__global__ __launch_bounds__(256) void prep(
    const float* __restrict__ x, __hip_bfloat16* __restrict__ xbt,
    const float* __restrict__ wq, const float* __restrict__ wk,
    const float* __restrict__ wv, const float* __restrict__ wo,
    __hip_bfloat16* __restrict__ wt) {
  __shared__ __hip_bfloat16 Lt[16384];  // 32KB (convert path)
  __shared__ float tile[32][33];        // 4.2KB (transpose path)
  if (blockIdx.x < 1024) {
    const int bid = blockIdx.x;  // = mblk*8 + kt
    const int mblk = bid >> 3, kt = bid & 7;
    const int t = threadIdx.x;
    const int koct = t & 7;
#pragma unroll
    for (int p = 0; p < 8; ++p) {
      int r = p * 32 + (t >> 3);
      const float* src =
          x + (size_t)(mblk * 256 + r) * 512 + kt * 64 + koct * 8;
      float4 f0 = *(const float4*)src;
      float4 f1 = *(const float4*)(src + 4);
      *(bf16x8*)&Lt[(koct * 256 + r) * 8] = cvt8(f0, f1);
    }
    __syncthreads();
    __hip_bfloat16* outb = xbt + (size_t)bid * 16384;
#pragma unroll
    for (int j = 0; j < 8; ++j) {
      int s = j * 256 + t;
      *(bf16x8*)(outb + (size_t)s * 8) = *(const bf16x8*)&Lt[s * 8];
    }
  } else {
    const int tb = blockIdx.x - 1024;      // 0..639
    const int n0 = (tb >> 4) * 32, k0 = (tb & 15) * 32;
    const float* W;
    int ld, nc;
    if (n0 < 512)      { W = wq; ld = 512; nc = n0; }
    else if (n0 < 640) { W = wk; ld = 128; nc = n0 - 512; }
    else if (n0 < 768) { W = wv; ld = 128; nc = n0 - 640; }
    else               { W = wo; ld = 512; nc = n0 - 768; }
    int xx = threadIdx.x & 31, y = threadIdx.x >> 5;
#pragma unroll
    for (int i = 0; i < 4; ++i)
      tile[y + 8 * i][xx] = W[(size_t)(k0 + y + 8 * i) * ld + nc + xx];
    __syncthreads();
#pragma unroll
    for (int i = 0; i < 4; ++i) {
      int n = n0 + y + 8 * i, k = k0 + xx;
      wt[((size_t)(n >> 7) << 16) +
         ((size_t)((k >> 3) * 128 + (n & 127))) * 8 + (k & 7)] =
          __float2bfloat16(tile[xx][y + 8 * i]);
    }
  }
}

// Wide-wave GEMM: BM128 x BN256, BK=32, 4 waves of 64x128 (2m x 2n),
// acc[4][8]. A tiled xbt-style (256-row mblk tiles, kt64 chunks; block uses
// half=mt&1). B spans two 128-col wt panels. C row-major, N = NT256*256.
template <int NT256, int NB0, typename OutT>
__global__ __launch_bounds__(256, 2) void gemm_wide(
    const __hip_bfloat16* __restrict__ At, const __hip_bfloat16* __restrict__ wt,
    OutT* __restrict__ C) {
  constexpr int N = NT256 * 256;
  __shared__ __hip_bfloat16 Al[2][4096];  // 2 x 8KB  [kg4][row128]
  __shared__ __hip_bfloat16 Bd[2][8192];  // 2 x 16KB [kg4][col256]
  const int tid = threadIdx.x;
  const int lane = tid & 63;
  const int w = tid >> 6;             // 0..3
  const int wr = w >> 1, wc = w & 1;  // 2m x 2n (wave 64 rows x 128 cols)
  constexpr int NWG = 256 * NT256;
  const int ng = (blockIdx.x & 7) * (NWG / 8) + (blockIdx.x >> 3);
  const int mt = ng / NT256;          // 0..255 (128-row tile)
  const int nt = ng % NT256;
  const int n0 = nt * 256;
  const int m0 = mt * 128;
  const int half = mt & 1;
  const __hip_bfloat16* Abase = At + (size_t)(mt >> 1) * 8 * 16384;

  const int kbq = lane >> 4, fr = lane & 15;
  f32x4 acc[4][8] = {};

  // stage K-tile kt32: 2 A + 4 B gloads per thread (16B each, 16-line/wave).
  auto stage = [&](int buf, int kt32) {
    const int kt64 = kt32 >> 1, kgo = (kt32 & 1) * 4;
    const __hip_bfloat16* As = Abase + (size_t)kt64 * 16384;
#pragma unroll
    for (int j = 0; j < 2; ++j) {
      int flat = j * 256 + tid;  // kg=flat>>7, row=flat&127
      int srcslot = (kgo + (flat >> 7)) * 256 + half * 128 + (flat & 127);
      gload_lds16(As + (size_t)srcslot * 8,
                  &Al[buf][(j * 256 + w * 64) * 8]);
    }
#pragma unroll
    for (int j = 0; j < 4; ++j) {
      int flat = j * 256 + tid;          // kg=flat>>8, col=flat&255
      int kg = flat >> 8, col = flat & 255;
      const __hip_bfloat16* src =
          wt + ((size_t)(NB0 + nt * 2 + (col >> 7)) << 16) +
          (size_t)kt64 * 8192 +
          (size_t)((kgo + kg) * 128 + (col & 127)) * 8;
      gload_lds16(src, &Bd[buf][(j * 256 + w * 64) * 8]);
    }
  };

  stage(0, 0);
  asm volatile("s_waitcnt vmcnt(0)" ::: "memory");
  __builtin_amdgcn_s_barrier();

#pragma unroll
  for (int kt = 0; kt < 16; ++kt) {
    const int cur = kt & 1;
    bf16x8 a[4], b[8];
#pragma unroll
    for (int mi = 0; mi < 4; ++mi)
      a[mi] = *(const bf16x8*)
          &Al[cur][(kbq * 128 + wr * 64 + mi * 16 + fr) * 8];
#pragma unroll
    for (int ni = 0; ni < 8; ++ni)
      b[ni] = *(const bf16x8*)
          &Bd[cur][(kbq * 256 + wc * 128 + ni * 16 + fr) * 8];
    if (kt < 15) stage(cur ^ 1, kt + 1);
    __builtin_amdgcn_s_setprio(1);
#pragma unroll
    for (int mi = 0; mi < 4; ++mi)
#pragma unroll
      for (int ni = 0; ni < 8; ++ni)
        acc[mi][ni] = __builtin_amdgcn_mfma_f32_16x16x32_bf16(
            a[mi], b[ni], acc[mi][ni], 0, 0, 0);
    __builtin_amdgcn_s_setprio(0);
    if (kt < 15) {
      asm volatile("s_waitcnt vmcnt(0)" ::: "memory");  // stage(kt+1) landed
      __builtin_amdgcn_s_barrier();  // all waves done reading buf cur
    }
  }

  // C/D layout: col=lane&15, row=(lane>>4)*4+reg  [m89]
#pragma unroll
  for (int mi = 0; mi < 4; ++mi) {
#pragma unroll
    for (int ni = 0; ni < 8; ++ni) {
      int col = n0 + wc * 128 + ni * 16 + (lane & 15);
#pragma unroll
      for (int r = 0; r < 4; ++r) {
        int row = m0 + wr * 64 + mi * 16 + (lane >> 4) * 4 + r;
        if constexpr (sizeof(OutT) == 2)
          C[(size_t)row * N + col] = __float2bfloat16(acc[mi][ni][r]);
        else
          C[(size_t)row * N + col] = acc[mi][ni][r];
      }
    }
  }
}

// attn with TILED output: block = 4 waves = 4 consecutive t-octs. Outputs
// bounce through padded LDS (idx' = idx + idx/8) then re-emit in xbt-tiled
// layout as 64B-contiguous runs.
__global__ __launch_bounds__(256) void attn_heads_t(
    const __hip_bfloat16* __restrict__ qkv, const float* __restrict__ fcos,
    const float* __restrict__ fsin, __hip_bfloat16* __restrict__ out2t) {
  __shared__ __hip_bfloat16 Ob[2304 * 8];  // 36KB padded
  const int lane = threadIdx.x & 63;
  const int w = threadIdx.x >> 6;
  const int wvid = blockIdx.x * 4 + w;  // = t-oct global index
  const int sub = lane >> 3, dlane = lane & 7;
  const int gt = wvid * 8 + sub;
  const int t = gt & 4095;
  const size_t row = (size_t)gt * 768;

  f32x4 c4 = *(const f32x4*)&fcos[(size_t)t * 32 + dlane * 4];
  f32x4 s4 = *(const f32x4*)&fsin[(size_t)t * 32 + dlane * 4];

  float q[8][8], k[2][8], v[2][8];
#pragma unroll
  for (int h = 0; h < 8; ++h) {
    ushort8 u = *(const ushort8*)&qkv[row + h * 64 + dlane * 8];
#pragma unroll
    for (int j = 0; j < 4; ++j) {
      float xr = bf2f(u[2 * j]), xi = bf2f(u[2 * j + 1]);
      q[h][2 * j] = xr * c4[j] - xi * s4[j];
      q[h][2 * j + 1] = xr * s4[j] + xi * c4[j];
    }
  }
#pragma unroll
  for (int c = 0; c < 2; ++c) {
    ushort8 uk = *(const ushort8*)&qkv[row + 512 + c * 64 + dlane * 8];
    ushort8 uv = *(const ushort8*)&qkv[row + 640 + c * 64 + dlane * 8];
#pragma unroll
    for (int j = 0; j < 4; ++j) {
      float xr = bf2f(uk[2 * j]), xi = bf2f(uk[2 * j + 1]);
      k[c][2 * j] = xr * c4[j] - xi * s4[j];
      k[c][2 * j + 1] = xr * s4[j] + xi * c4[j];
    }
#pragma unroll
    for (int j = 0; j < 8; ++j) v[c][j] = bf2f(uv[j]);
  }

  float dot[8][2];
#pragma unroll
  for (int h = 0; h < 8; ++h)
#pragma unroll
    for (int c = 0; c < 2; ++c) {
      float p = 0.f;
#pragma unroll
      for (int j = 0; j < 8; ++j) p += q[h][j] * k[c][j];
      p += __shfl_xor(p, 1);
      p += __shfl_xor(p, 2);
      p += __shfl_xor(p, 4);
      dot[h][c] = p * 0.125f;  // 1/sqrt(64)
    }

#pragma unroll
  for (int h = 0; h < 8; ++h) {
    int c0 = (h + 1 < 4) ? (h + 1) : 4;
    int c1 = (h + 1) - c0;
    float w0, w1;
    if (c1 > 0) {
      float s0 = dot[h][0], s1 = dot[h][1];
      float m = fmaxf(s0, s1);
      float e0 = (float)c0 * expf(s0 - m), e1 = (float)c1 * expf(s1 - m);
      float inv = 1.f / (e0 + e1);
      w0 = e0 * inv;
      w1 = e1 * inv;
    } else {
      w0 = 1.f;
      w1 = 0.f;
    }
    bf16x8 o;
#pragma unroll
    for (int j = 0; j < 8; ++j)
      o[j] = (__bf16)(w0 * v[0][j] + w1 * v[1][j]);
    int idx = ((w * 8 + h) * 8 + sub) * 8 + dlane;
    *(bf16x8*)&Ob[(idx + (idx >> 3)) * 8] = o;
  }

  __syncthreads();

  // store phase: thread = (h2, sub2, oi); loop dlane. 4 consecutive rows
  // (oi) -> 64B-contiguous tiled runs.
  const int b = blockIdx.x >> 7;            // 1024 blocks = 8 batches
  const int wbase = (blockIdx.x * 4) & 511; // t-oct base within batch
  const int h2 = threadIdx.x >> 5;
  const int sub2 = (threadIdx.x >> 2) & 7;
  const int oi = threadIdx.x & 3;
  const int R = b * 4096 + h2 * 512 + wbase + oi;
  const size_t dbase = ((size_t)((R >> 8) * 8 + sub2)) * 2048 + (R & 255);
#pragma unroll
  for (int dl = 0; dl < 8; ++dl) {
    int idx = ((oi * 8 + h2) * 8 + sub2) * 8 + dl;
    *(bf16x8*)&out2t[(dbase + dl * 256) * 8] =
        *(const bf16x8*)&Ob[(idx + (idx >> 3)) * 8];
  }
}

extern "C" void kernel_launch(void* const* d_in, const int* in_sizes, int n_in,
                              void* d_out, int out_size, void* d_ws,
                              size_t ws_size, hipStream_t stream) {
  const float* x    = (const float*)d_in[0];
  const float* fcos = (const float*)d_in[1];
  const float* fsin = (const float*)d_in[2];
  const float* wq   = (const float*)d_in[3];
  const float* wk   = (const float*)d_in[4];
  const float* wv   = (const float*)d_in[5];
  const float* wo   = (const float*)d_in[6];
  float* out = (float*)d_out;

  __hip_bfloat16* xbt   = (__hip_bfloat16*)d_ws;  // 32MB (tiled)
  __hip_bfloat16* out2t = xbt;                     // alias (dead after gemm6)
  __hip_bfloat16* qkv   = (__hip_bfloat16*)((char*)d_ws + (size_t)M_TOT * 512 * 2);  // 48MB
  __hip_bfloat16* wt    = (__hip_bfloat16*)((char*)d_ws + (size_t)M_TOT * 512 * 2 +
                                            (size_t)M_TOT * 768 * 2);  // 1.31MB

  prep<<<dim3(1664), 256, 0, stream>>>(x, xbt, wq, wk, wv, wo, wt);
  gemm_wide<3, 0, __hip_bfloat16><<<dim3(768), 256, 0, stream>>>(xbt, wt, qkv);
  attn_heads_t<<<dim3(M_TOT / 8 / 4), 256, 0, stream>>>(qkv, fcos, fsin, out2t);
  gemm_wide<2, 6, float><<<dim3(512), 256, 0, stream>>>(out2t, wt, out);
}